// Round 2
// baseline (593.853 us; speedup 1.0000x reference)
//
#include <hip/hip_runtime.h>
#include <hip/hip_bf16.h>

typedef unsigned short u16;
typedef __bf16 bf16x8 __attribute__((ext_vector_type(8)));
typedef float f32x4 __attribute__((ext_vector_type(4)));

#define N_NODES 200000
#define IN_FEAT 500
#define EMB 128
#define HID 64
#define NC 7
#define BM 64          // rows per block
#define KPAD 512       // 500 padded to 16 chunks of 32

// LDS strides (bf16 elements) — padded so consecutive fragment rows land on
// different banks (<=2-way aliasing, which is free on gfx950)
#define FS 40          // F chunk   [64][40]
#define WS 40          // W chunk   [128][40]
#define W1S 136        // Wt1       [64][136]
#define ES 136         // emb tile  [64][136]
#define HS 72          // h tile    [64][72]
#define W2S 72         // Wt2       [16][72]

// d_ws layout (u16 elements): Wt_emb[128][512] | Wt1[64][128] | Wt2[16][64]
#define WS_WT1_OFF (128*512)
#define WS_WT2_OFF (128*512 + 64*128)
#define WS_TOTAL   (128*512 + 64*128 + 16*64)

__device__ __forceinline__ u16 cvt_bf16(float v) {
    __hip_bfloat16 h = __float2bfloat16(v);
    return *(u16*)&h;
}

__global__ __launch_bounds__(256) void prep_weights(
    const float* __restrict__ W_emb, const float* __restrict__ W_rt1,
    const float* __restrict__ W_rt2, u16* __restrict__ ws)
{
    int idx = blockIdx.x * 256 + threadIdx.x;
    float v;
    bool ok = true;
    if (idx < 128*512) {                       // Wt_emb[n][k], zero-pad k>=500
        int n = idx >> 9, k = idx & 511;
        v = (k < IN_FEAT) ? W_emb[k*EMB + n] : 0.f;
    } else if (idx < WS_WT2_OFF) {             // Wt1[n][k]
        int j = idx - WS_WT1_OFF;
        int n = j >> 7, k = j & 127;
        v = W_rt1[k*HID + n];
    } else if (idx < WS_TOTAL) {               // Wt2[n][k], zero-pad n>=7
        int j = idx - WS_WT2_OFF;
        int n = j >> 6, k = j & 63;
        v = (n < NC) ? W_rt2[k*NC + n] : 0.f;
    } else {
        ok = false;
        v = 0.f;
    }
    if (ok) ws[idx] = cvt_bf16(v);
}

__global__ __launch_bounds__(256) void mlp_fused(
    const float* __restrict__ F, const u16* __restrict__ Wt_emb,
    const u16* __restrict__ Wt1g, const u16* __restrict__ Wt2g,
    const float* __restrict__ b_emb, const float* __restrict__ b1,
    const float* __restrict__ b2, float* __restrict__ out)
{
    __shared__ u16 Fch[BM * FS];
    __shared__ u16 Wch[EMB * WS];
    __shared__ u16 W1l[HID * W1S];
    __shared__ u16 W2l[16 * W2S];
    __shared__ u16 Et[BM * ES];
    __shared__ u16 Ht[BM * HS];

    const int tid  = threadIdx.x;
    const int wave = tid >> 6;
    const int lane = tid & 63;
    const int l15  = lane & 15;
    const int q    = lane >> 4;            // quad 0..3
    const int row0 = blockIdx.x * BM;

    // ---- stage Wt1 (64x128) and Wt2 (16x64) into LDS once (bf16) ----
    #pragma unroll
    for (int i = 0; i < 4; ++i) {
        int g = tid * 4 + i;               // 1024 groups of 8 elems
        int r = g >> 4, cc = (g & 15) * 8;
        *(uint4*)&W1l[r*W1S + cc] = *(const uint4*)&Wt1g[r*128 + cc];
    }
    if (tid < 128) {
        int r = tid >> 3, cc = (tid & 7) * 8;
        *(uint4*)&W2l[r*W2S + cc] = *(const uint4*)&Wt2g[r*64 + cc];
    }

    // ---- layer 1: emb = relu(F @ W_emb + b_emb), K=512 (padded) ----
    f32x4 acc[8];
    #pragma unroll
    for (int t = 0; t < 8; ++t) acc[t] = (f32x4){0.f,0.f,0.f,0.f};

    for (int c = 0; c < 16; ++c) {
        const int k0 = c * 32;
        // stage F chunk [64][32] fp32 -> bf16: thread -> row tid>>2, group tid&3
        {
            int r = tid >> 2, g = tid & 3;
            const float* src = F + (size_t)(row0 + r) * IN_FEAT + k0 + g * 8;
            union { u16 u[8]; uint4 v4; } pk;
            if (c < 15 || g < 2) {
                // row stride 2000B and offsets are 16B aligned -> float4 loads
                float4 f0 = *(const float4*)(src);
                float4 f1 = *(const float4*)(src + 4);
                pk.u[0] = cvt_bf16(f0.x); pk.u[1] = cvt_bf16(f0.y);
                pk.u[2] = cvt_bf16(f0.z); pk.u[3] = cvt_bf16(f0.w);
                pk.u[4] = cvt_bf16(f1.x); pk.u[5] = cvt_bf16(f1.y);
                pk.u[6] = cvt_bf16(f1.z); pk.u[7] = cvt_bf16(f1.w);
            } else {
                #pragma unroll
                for (int j = 0; j < 8; ++j) {
                    int k = k0 + g * 8 + j;
                    pk.u[j] = (k < IN_FEAT) ? cvt_bf16(src[j]) : (u16)0;
                }
            }
            *(uint4*)&Fch[r*FS + g*8] = pk.v4;
        }
        // stage W chunk [128][32] from pre-transposed bf16 Wt_emb
        {
            int n = tid >> 1, h = (tid & 1) * 16;
            *(uint4*)&Wch[n*WS + h]     = *(const uint4*)&Wt_emb[n*KPAD + k0 + h];
            *(uint4*)&Wch[n*WS + h + 8] = *(const uint4*)&Wt_emb[n*KPAD + k0 + h + 8];
        }
        __syncthreads();

        bf16x8 a = *(const bf16x8*)&Fch[(wave*16 + l15)*FS + q*8];
        #pragma unroll
        for (int t = 0; t < 8; ++t) {
            bf16x8 b = *(const bf16x8*)&Wch[(t*16 + l15)*WS + q*8];
            acc[t] = __builtin_amdgcn_mfma_f32_16x16x32_bf16(a, b, acc[t], 0, 0, 0);
        }
        __syncthreads();
    }

    // epilogue 1: bias + relu -> bf16 emb tile in LDS
    #pragma unroll
    for (int t = 0; t < 8; ++t) {
        float bias = b_emb[t*16 + l15];
        #pragma unroll
        for (int r = 0; r < 4; ++r) {
            float v = acc[t][r] + bias;
            v = v > 0.f ? v : 0.f;
            Et[(wave*16 + q*4 + r)*ES + t*16 + l15] = cvt_bf16(v);
        }
    }
    __syncthreads();

    // ---- layer 2: h = relu(emb @ W_rt1 + b1), K=128 ----
    f32x4 acc2[4];
    #pragma unroll
    for (int t = 0; t < 4; ++t) acc2[t] = (f32x4){0.f,0.f,0.f,0.f};
    #pragma unroll
    for (int kc = 0; kc < 4; ++kc) {
        bf16x8 a = *(const bf16x8*)&Et[(wave*16 + l15)*ES + kc*32 + q*8];
        #pragma unroll
        for (int t = 0; t < 4; ++t) {
            bf16x8 b = *(const bf16x8*)&W1l[(t*16 + l15)*W1S + kc*32 + q*8];
            acc2[t] = __builtin_amdgcn_mfma_f32_16x16x32_bf16(a, b, acc2[t], 0, 0, 0);
        }
    }
    #pragma unroll
    for (int t = 0; t < 4; ++t) {
        float bias = b1[t*16 + l15];
        #pragma unroll
        for (int r = 0; r < 4; ++r) {
            float v = acc2[t][r] + bias;
            v = v > 0.f ? v : 0.f;
            Ht[(wave*16 + q*4 + r)*HS + t*16 + l15] = cvt_bf16(v);
        }
    }
    __syncthreads();

    // ---- layer 3: out = h @ W_rt2 + b2, K=64, N=7 (padded to 16) ----
    f32x4 acc3 = (f32x4){0.f,0.f,0.f,0.f};
    #pragma unroll
    for (int kc = 0; kc < 2; ++kc) {
        bf16x8 a = *(const bf16x8*)&Ht[(wave*16 + l15)*HS + kc*32 + q*8];
        bf16x8 b = *(const bf16x8*)&W2l[l15*W2S + kc*32 + q*8];
        acc3 = __builtin_amdgcn_mfma_f32_16x16x32_bf16(a, b, acc3, 0, 0, 0);
    }
    if (l15 < NC) {
        float bias = b2[l15];
        #pragma unroll
        for (int r = 0; r < 4; ++r) {
            float v = acc3[r] + bias;
            out[(size_t)(row0 + wave*16 + q*4 + r) * NC + l15] = v;
        }
    }
}

extern "C" void kernel_launch(void* const* d_in, const int* in_sizes, int n_in,
                              void* d_out, int out_size, void* d_ws, size_t ws_size,
                              hipStream_t stream) {
    // inputs: 0=adj(unused) 1=features 2=W_emb 3=b_emb 4=W_rt1 5=b_rt1 6=W_rt2 7=b_rt2
    const float* F     = (const float*)d_in[1];
    const float* W_emb = (const float*)d_in[2];
    const float* b_emb = (const float*)d_in[3];
    const float* W_rt1 = (const float*)d_in[4];
    const float* b_rt1 = (const float*)d_in[5];
    const float* W_rt2 = (const float*)d_in[6];
    const float* b_rt2 = (const float*)d_in[7];
    u16* ws    = (u16*)d_ws;
    float* out = (float*)d_out;

    int prep_blocks = (WS_TOTAL + 255) / 256;
    prep_weights<<<prep_blocks, 256, 0, stream>>>(W_emb, W_rt1, W_rt2, ws);

    mlp_fused<<<N_NODES / BM, 256, 0, stream>>>(
        F, ws, ws + WS_WT1_OFF, ws + WS_WT2_OFF,
        b_emb, b_rt1, b_rt2, out);
}